// Round 1
// 299.972 us; speedup vs baseline: 1.0408x; 1.0408x over previous
//
#include <hip/hip_runtime.h>
#include <cstdint>

#define PN 196   // 14*14 patches
#define PC 768   // channels
#define KC 16    // channel rows staged per chunk

// ---------------------------------------------------------------------------
// Kernel 1: partial channel reduction. grid (NCH, B). Each block reduces
// PC/NCH channels of one batch into 3 partial dot-product rows (symmetry:
// acc_l[n] = acc_r[n-1], acc_u[n] = acc_d[n-14], so only s/r/d needed):
//   acc_s[n] = sum_c S[c][n]^2
//   acc_r[n] = sum_c S[c][n]*S[c][n+1]   (valid where j<13)
//   acc_d[n] = sum_c S[c][n]*S[c][n+14]  (valid where i<13)
// ---------------------------------------------------------------------------
template<int NCH>
__global__ __launch_bounds__(256) void adb_reduce(
    const float* __restrict__ S, float* __restrict__ partials)
{
    constexpr int CPB = PC / NCH;
    const int b   = blockIdx.y;
    const int ch  = blockIdx.x;
    const int tid = threadIdx.x;

    __shared__ float rows[KC * PN];

    const float* Sb = S + (size_t)b * PC * PN + (size_t)ch * CPB * PN;

    const bool lane = tid < PN;
    const int n = lane ? tid : 0;
    const int i = n / 14, j = n % 14;
    const bool has_r = lane && (j < 13);
    const bool has_d = lane && (i < 13);
    const int ir = n + (has_r ? 1  : 0);
    const int id = n + (has_d ? 14 : 0);

    float acc_s = 0.f, acc_r = 0.f, acc_d = 0.f;

    for (int c0 = 0; c0 < CPB; c0 += KC) {
        __syncthreads();
        const float4* src = (const float4*)(Sb + c0 * PN);
        float4* dst = (float4*)rows;
        #pragma unroll
        for (int k = 0; k < 4; k++) {            // 784 float4s, 256 threads
            int idx = tid + k * 256;
            if (idx < KC * PN / 4) dst[idx] = src[idx];
        }
        __syncthreads();
        if (lane) {
            #pragma unroll
            for (int cc = 0; cc < KC; cc++) {
                const float* r = rows + cc * PN;
                float s = r[n];
                acc_s += s * s;
                acc_r += s * r[ir];
                acc_d += s * r[id];
            }
        }
    }

    if (lane) {
        float* P = partials + ((size_t)b * NCH + ch) * 3 * PN;
        P[0 * PN + n] = acc_s;
        P[1 * PN + n] = acc_r;
        P[2 * PN + n] = acc_d;
    }
}

// ---------------------------------------------------------------------------
// Kernel 2: per-batch solve. Sum partials, reconstruct the 5-coeff sparse
// Laplacian row (left/up from neighbor's r/d sums via LDS), run factored
// Newton-Schulz
//   X4 = X0 (I+R0)(I+R0^2)(I+R0^4)(I+R0^8),  R0 = I - 0.01 L^2
// applied to attn*5 as 31 stencil matvecs. Vector state lives in registers;
// LDS holds only the ping-pong matvec source => ONE barrier per matvec.
// Emit Fmap and G = 1+Fdiff.
// ---------------------------------------------------------------------------
template<int NCH>
__global__ __launch_bounds__(256) void adb_solve(
    const float* __restrict__ partials, const float* __restrict__ attn,
    const float* __restrict__ lmbd, const float* __restrict__ beta,
    float* __restrict__ Fmap, float* __restrict__ Gmap)
{
    const int b   = blockIdx.x;
    const int tid = threadIdx.x;

    __shared__ float rnorm[PN];
    __shared__ float srs[PN];     // summed acc_r
    __shared__ float sds[PN];     // summed acc_d
    __shared__ float buf[2][PN];  // matvec ping-pong

    const bool lane = tid < PN;
    const int n = lane ? tid : 0;
    const int i = n / 14, j = n % 14;
    const bool has_l = lane && (j > 0);
    const bool has_r = lane && (j < 13);
    const bool has_u = lane && (i > 0);
    const bool has_d = lane && (i < 13);
    const int il = n - (has_l ? 1  : 0);
    const int ir = n + (has_r ? 1  : 0);
    const int iu = n - (has_u ? 14 : 0);
    const int id = n + (has_d ? 14 : 0);

    float acc_s = 0.f, acc_r = 0.f, acc_d = 0.f;
    if (lane) {
        const float* P = partials + (size_t)b * NCH * 3 * PN;
        #pragma unroll
        for (int ch = 0; ch < NCH; ch++) {
            const float* Pc = P + ch * 3 * PN;
            acc_s += Pc[0 * PN + n];
            acc_r += Pc[1 * PN + n];
            acc_d += Pc[2 * PN + n];
        }
    }

    const float lm = lmbd[0];
    const float bt = beta[0];

    float rn = 0.f, va = 0.f;
    if (lane) {
        rn = 1.0f / fmaxf(sqrtf(acc_s), 1e-12f);
        rnorm[n] = rn;
        srs[n]   = acc_r;
        sds[n]   = acc_d;
        va = attn[(size_t)b * PN + n] * 5.0f;
    }
    __syncthreads();

    float Lc = 0.f, Ll = 0.f, Lr = 0.f, Lu = 0.f, Ld = 0.f;
    if (lane) {
        float deg = (float)((has_l?1:0) + (has_r?1:0) + (has_u?1:0) + (has_d?1:0));
        float Enn = (acc_s * rn * rn + 1.f) * 0.5f;
        Lc = deg * (lm * Enn - 1.f) + 1e-6f;
        if (has_r) Lr = 1.f - lm * ((acc_r   * rn * rnorm[ir] + 1.f) * 0.5f);
        if (has_l) Ll = 1.f - lm * ((srs[il] * rn * rnorm[il] + 1.f) * 0.5f);
        if (has_d) Ld = 1.f - lm * ((acc_d   * rn * rnorm[id] + 1.f) * 0.5f);
        if (has_u) Lu = 1.f - lm * ((sds[iu] * rn * rnorm[iu] + 1.f) * 0.5f);
    }

    // One barrier per matvec. Safety of single barrier: call k writes
    // buf[p_k], barriers, reads buf[p_k]. Call k+1 writes the OTHER buffer;
    // call k+2's overwrite of buf[p_k] is separated from call k's reads by
    // the barrier inside call k+1.
    int p = 0;
    auto mv = [&](float src) -> float {
        if (lane) buf[p][n] = src;
        __syncthreads();
        float r = 0.f;
        if (lane) {
            r = Lc * buf[p][n]  + Ll * buf[p][il] + Lr * buf[p][ir]
              + Lu * buf[p][iu] + Ld * buf[p][id];
        }
        p ^= 1;
        return r;
    };

    // vv = X0 a = 0.01 * L a
    float vv = 0.01f * mv(va);

    // vv <- (I + R0^(2^stage)) vv,  R0 = I - 0.01 L^2
    #pragma unroll
    for (int stage = 0; stage < 4; stage++) {
        float w = vv;
        const int k = 1 << stage;
        for (int it = 0; it < k; it++) {
            float t  = mv(w);
            float s2 = mv(t);
            w -= 0.01f * s2;
        }
        vv += w;
    }

    if (lane) {
        float Fd = vv;
        float Fdiff = bt * (Fd - tanhf(Fd / (bt + 1e-8f)));
        Fmap[(size_t)b * PN + n] = Fdiff;
        Gmap[(size_t)b * PN + n] = 1.0f + Fdiff;
    }
}

// ---------------------------------------------------------------------------
// Kernel 3: S_new = S * G. grid (147, B): each block handles 1024 consecutive
// floats of one batch; G row (196 floats + 3 wrap) staged in LDS.
// ---------------------------------------------------------------------------
__global__ __launch_bounds__(256) void adb_scale(
    const float* __restrict__ S, const float* __restrict__ Gmap,
    float* __restrict__ out)
{
    const int b   = blockIdx.y;
    const int tid = threadIdx.x;

    __shared__ float Gs[PN + 3];
    const float* Gb = Gmap + (size_t)b * PN;
    if (tid < PN / 4) ((float4*)Gs)[tid] = ((const float4*)Gb)[tid];
    if (tid >= 64 && tid < 67) Gs[PN + (tid - 64)] = Gb[tid - 64];  // wrap
    __syncthreads();

    const int off = blockIdx.x * 1024 + tid * 4;   // < 150528
    const int n0  = off % PN;                      // magic-mul, constant PN
    const size_t base = (size_t)b * PC * PN + off;
    float4 sv = *(const float4*)(S + base);
    float4 o;
    o.x = sv.x * Gs[n0];
    o.y = sv.y * Gs[n0 + 1];
    o.z = sv.z * Gs[n0 + 2];
    o.w = sv.w * Gs[n0 + 3];
    *(float4*)(out + base) = o;
}

extern "C" void kernel_launch(void* const* d_in, const int* in_sizes, int n_in,
                              void* d_out, int out_size, void* d_ws, size_t ws_size,
                              hipStream_t stream) {
    const float* S    = (const float*)d_in[0];
    const float* attn = (const float*)d_in[1];
    const float* lmbd = (const float*)d_in[2];
    const float* beta = (const float*)d_in[3];

    const int B = in_sizes[1] / PN;                    // 256

    float* Snew = (float*)d_out;                       // [B,C,14,14]
    float* Fmap = (float*)d_out + (size_t)B * PC * PN; // [B,1,14,14]
    float* ws   = (float*)d_ws;

    const size_t need8 = ((size_t)B * 8 * 3 * PN + (size_t)B * PN) * sizeof(float);
    const size_t need2 = ((size_t)B * 2 * 3 * PN + (size_t)B * PN) * sizeof(float);
    const size_t need1 = ((size_t)B * 1 * 3 * PN + (size_t)B * PN) * sizeof(float);

    if (ws_size >= need8) {
        float* partials = ws;
        float* Gmap = ws + (size_t)B * 8 * 3 * PN;
        adb_reduce<8><<<dim3(8, B), 256, 0, stream>>>(S, partials);
        adb_solve<8><<<B, 256, 0, stream>>>(partials, attn, lmbd, beta, Fmap, Gmap);
        adb_scale<<<dim3((PC * PN) / 1024, B), 256, 0, stream>>>(S, Gmap, Snew);
    } else if (ws_size >= need2) {
        float* partials = ws;
        float* Gmap = ws + (size_t)B * 2 * 3 * PN;
        adb_reduce<2><<<dim3(2, B), 256, 0, stream>>>(S, partials);
        adb_solve<2><<<B, 256, 0, stream>>>(partials, attn, lmbd, beta, Fmap, Gmap);
        adb_scale<<<dim3((PC * PN) / 1024, B), 256, 0, stream>>>(S, Gmap, Snew);
    } else {
        // minimal-scratch fallback
        float* partials = ws;
        float* Gmap = ws + (size_t)B * 1 * 3 * PN;
        (void)need1;
        adb_reduce<1><<<dim3(1, B), 256, 0, stream>>>(S, partials);
        adb_solve<1><<<B, 256, 0, stream>>>(partials, attn, lmbd, beta, Fmap, Gmap);
        adb_scale<<<dim3((PC * PN) / 1024, B), 256, 0, stream>>>(S, Gmap, Snew);
    }
}

// Round 2
// 299.734 us; speedup vs baseline: 1.0416x; 1.0008x over previous
//
#include <hip/hip_runtime.h>
#include <cstdint>

#define PN 196   // 14*14 patches
#define PC 768   // channels
#define KC 16    // channel rows staged per chunk

// ---------------------------------------------------------------------------
// Kernel 1: partial channel reduction. grid (NCH, B). Each block reduces
// PC/NCH channels of one batch into 3 partial dot-product rows (symmetry:
// acc_l[n] = acc_r[n-1], acc_u[n] = acc_d[n-14], so only s/r/d needed):
//   acc_s[n] = sum_c S[c][n]^2
//   acc_r[n] = sum_c S[c][n]*S[c][n+1]   (consumed only where j<13)
//   acc_d[n] = sum_c S[c][n]*S[c][n+14]  (consumed only where i<13)
// Reads are UNCONDITIONAL with a 16-float LDS pad: boundary lanes compute
// garbage acc_r (j==13) / acc_d (i==13) that the solve provably never reads
// (it only consults srs[il] with j(il)<=12 and sds[iu] with i(iu)<=12).
// One vaddr + constant byte offsets per cc => minimal VALU, ds_read2 merge.
// ---------------------------------------------------------------------------
template<int NCH>
__global__ __launch_bounds__(256) void adb_reduce(
    const float* __restrict__ S, float* __restrict__ partials)
{
    constexpr int CPB = PC / NCH;
    const int b   = blockIdx.y;
    const int ch  = blockIdx.x;
    const int tid = threadIdx.x;

    __shared__ __align__(16) float rows[KC * PN + 16];

    const float* Sb = S + (size_t)b * PC * PN + (size_t)ch * CPB * PN;

    const bool lane = tid < PN;
    const int n = lane ? tid : 0;

    float acc_s = 0.f, acc_r = 0.f, acc_d = 0.f;

    for (int c0 = 0; c0 < CPB; c0 += KC) {
        __syncthreads();
        const float4* src = (const float4*)(Sb + c0 * PN);
        float4* dst = (float4*)rows;
        #pragma unroll
        for (int k = 0; k < 4; k++) {            // 784 float4s, 256 threads
            int idx = tid + k * 256;
            if (idx < KC * PN / 4) dst[idx] = src[idx];
        }
        __syncthreads();
        if (lane) {
            const float* r0 = rows + n;
            #pragma unroll
            for (int cc = 0; cc < KC; cc++) {
                const float* r = r0 + cc * PN;
                float s = r[0];
                acc_s += s * s;
                acc_r += s * r[1];
                acc_d += s * r[14];
            }
        }
    }

    if (lane) {
        float* P = partials + ((size_t)b * NCH + ch) * 3 * PN;
        P[0 * PN + n] = acc_s;
        P[1 * PN + n] = acc_r;
        P[2 * PN + n] = acc_d;
    }
}

// ---------------------------------------------------------------------------
// Kernel 2: per-batch solve, ONE WAVE per batch, ZERO barriers.
// Lane L (0..48) owns a 2x2 node block at (2*i2, 2*j2), i2=L/7, j2=L%7:
//   k=0: (2i2,2j2)  k=1: (2i2,2j2+1)  k=2: (2i2+1,2j2)  k=3: (2i2+1,2j2+1)
// All neighbor exchange is 8 __shfl per matvec; boundary lanes clamp the
// shuffle source to themselves (coefficient is 0 there, value just needs to
// be finite). Factored Newton-Schulz as before:
//   X4 = X0 (I+R0)(I+R0^2)(I+R0^4)(I+R0^8),  R0 = I - 0.01 L^2
// ---------------------------------------------------------------------------
template<int NCH>
__global__ __launch_bounds__(64) void adb_solve(
    const float* __restrict__ partials, const float* __restrict__ attn,
    const float* __restrict__ lmbd, const float* __restrict__ beta,
    float* __restrict__ Fmap, float* __restrict__ Gmap)
{
    const int b  = blockIdx.x;
    const int L  = threadIdx.x;           // 0..63, active 0..48
    const int i2 = L / 7, j2 = L % 7;
    const bool act = (L < 49) && (i2 < 7);

    const int n00 = act ? ((2 * i2) * 14 + 2 * j2) : 0;
    const int nn0 = n00, nn1 = n00 + 1, nn2 = n00 + 14, nn3 = n00 + 15;

    // --- gather partial sums for the 4 owned nodes -------------------------
    float as0 = 0.f, as1 = 0.f, as2 = 0.f, as3 = 0.f;
    float ar0 = 0.f, ar1 = 0.f, ar2 = 0.f, ar3 = 0.f;
    float ad0 = 0.f, ad1 = 0.f, ad2 = 0.f, ad3 = 0.f;
    if (act) {
        const float* P = partials + (size_t)b * NCH * 3 * PN;
        #pragma unroll
        for (int ch = 0; ch < NCH; ch++) {
            const float* Pc = P + ch * 3 * PN;
            as0 += Pc[nn0]; as1 += Pc[nn1]; as2 += Pc[nn2]; as3 += Pc[nn3];
            ar0 += Pc[PN + nn0]; ar1 += Pc[PN + nn1];
            ar2 += Pc[PN + nn2]; ar3 += Pc[PN + nn3];
            ad0 += Pc[2 * PN + nn0]; ad1 += Pc[2 * PN + nn1];
            ad2 += Pc[2 * PN + nn2]; ad3 += Pc[2 * PN + nn3];
        }
    }

    const float lm = lmbd[0];
    const float bt = beta[0];

    float rn0 = 1.0f / fmaxf(sqrtf(as0), 1e-12f);
    float rn1 = 1.0f / fmaxf(sqrtf(as1), 1e-12f);
    float rn2 = 1.0f / fmaxf(sqrtf(as2), 1e-12f);
    float rn3 = 1.0f / fmaxf(sqrtf(as3), 1e-12f);

    // clamped shuffle source lanes (clamp => coefficient is 0 on that edge)
    const int sl_l = (j2 > 0) ? L - 1 : L;
    const int sl_r = (j2 < 6) ? L + 1 : L;
    const int sl_u = (i2 > 0) ? L - 7 : L;
    const int sl_d = (i2 < 6) ? L + 7 : L;

    // neighbor norms / sums needed for coefficient construction
    float rnL0 = __shfl(rn1, sl_l, 64);   // left  of n00 = (L-1).n01
    float rnL2 = __shfl(rn3, sl_l, 64);   // left  of n10 = (L-1).n11
    float rnR1 = __shfl(rn0, sl_r, 64);   // right of n01 = (L+1).n00
    float rnR3 = __shfl(rn2, sl_r, 64);   // right of n11 = (L+1).n10
    float rnU0 = __shfl(rn2, sl_u, 64);   // up    of n00 = (L-7).n10
    float rnU1 = __shfl(rn3, sl_u, 64);   // up    of n01 = (L-7).n11
    float rnD2 = __shfl(rn0, sl_d, 64);   // down  of n10 = (L+7).n00
    float rnD3 = __shfl(rn1, sl_d, 64);   // down  of n11 = (L+7).n01
    float srL0 = __shfl(ar1, sl_l, 64);   // srs[il] for n00
    float srL2 = __shfl(ar3, sl_l, 64);   // srs[il] for n10
    float sdU0 = __shfl(ad2, sl_u, 64);   // sds[iu] for n00
    float sdU1 = __shfl(ad3, sl_u, 64);   // sds[iu] for n01

    // per-node edge masks (global coords: i = 2*i2 + (k>>1), j = 2*j2 + (k&1))
    const bool hl0 = (j2 > 0), hl2 = (j2 > 0);
    const bool hr1 = (j2 < 6), hr3 = (j2 < 6);
    const bool hu0 = (i2 > 0), hu1 = (i2 > 0);
    const bool hd2 = (i2 < 6), hd3 = (i2 < 6);

    const float deg0 = (hl0 ? 1.f : 0.f) + 1.f + (hu0 ? 1.f : 0.f) + 1.f;
    const float deg1 = 1.f + (hr1 ? 1.f : 0.f) + (hu1 ? 1.f : 0.f) + 1.f;
    const float deg2 = (hl2 ? 1.f : 0.f) + 1.f + 1.f + (hd2 ? 1.f : 0.f);
    const float deg3 = 1.f + (hr3 ? 1.f : 0.f) + 1.f + (hd3 ? 1.f : 0.f);

    auto cdiag = [&](float as, float rn, float deg) {
        float Enn = (as * rn * rn + 1.f) * 0.5f;
        return deg * (lm * Enn - 1.f) + 1e-6f;
    };
    auto coff = [&](float dot, float rna, float rnb) {
        return 1.f - lm * ((dot * rna * rnb + 1.f) * 0.5f);
    };

    const float Lc0 = cdiag(as0, rn0, deg0);
    const float Lc1 = cdiag(as1, rn1, deg1);
    const float Lc2 = cdiag(as2, rn2, deg2);
    const float Lc3 = cdiag(as3, rn3, deg3);

    const float Ll0 = hl0 ? coff(srL0, rn0, rnL0) : 0.f;
    const float Ll1 =       coff(ar0,  rn1, rn0);         // il = n00 (own)
    const float Ll2 = hl2 ? coff(srL2, rn2, rnL2) : 0.f;
    const float Ll3 =       coff(ar2,  rn3, rn2);         // il = n10 (own)

    const float Lr0 =       coff(ar0,  rn0, rn1);         // ir = n01 (own)
    const float Lr1 = hr1 ? coff(ar1,  rn1, rnR1) : 0.f;
    const float Lr2 =       coff(ar2,  rn2, rn3);         // ir = n11 (own)
    const float Lr3 = hr3 ? coff(ar3,  rn3, rnR3) : 0.f;

    const float Lu0 = hu0 ? coff(sdU0, rn0, rnU0) : 0.f;
    const float Lu1 = hu1 ? coff(sdU1, rn1, rnU1) : 0.f;
    const float Lu2 =       coff(ad0,  rn2, rn0);         // iu = n00 (own)
    const float Lu3 =       coff(ad1,  rn3, rn1);         // iu = n01 (own)

    const float Ld0 =       coff(ad0,  rn0, rn2);         // id = n10 (own)
    const float Ld1 =       coff(ad1,  rn1, rn3);         // id = n11 (own)
    const float Ld2 = hd2 ? coff(ad2,  rn2, rnD2) : 0.f;
    const float Ld3 = hd3 ? coff(ad3,  rn3, rnD3) : 0.f;

    // barrier-free stencil matvec: y = L x (4 nodes per lane, 8 shuffles)
    auto mv = [&](float& y0, float& y1, float& y2, float& y3,
                  float x0, float x1, float x2, float x3) {
        float xl0 = __shfl(x1, sl_l, 64);
        float xl2 = __shfl(x3, sl_l, 64);
        float xr1 = __shfl(x0, sl_r, 64);
        float xr3 = __shfl(x2, sl_r, 64);
        float xu0 = __shfl(x2, sl_u, 64);
        float xu1 = __shfl(x3, sl_u, 64);
        float xd2 = __shfl(x0, sl_d, 64);
        float xd3 = __shfl(x1, sl_d, 64);
        y0 = Lc0 * x0 + Ll0 * xl0 + Lr0 * x1  + Lu0 * xu0 + Ld0 * x2;
        y1 = Lc1 * x1 + Ll1 * x0  + Lr1 * xr1 + Lu1 * xu1 + Ld1 * x3;
        y2 = Lc2 * x2 + Ll2 * xl2 + Lr2 * x3  + Lu2 * x0  + Ld2 * xd2;
        y3 = Lc3 * x3 + Ll3 * x2  + Lr3 * xr3 + Lu3 * x1  + Ld3 * xd3;
    };

    // a = attn * 5
    float a0 = 0.f, a1 = 0.f, a2 = 0.f, a3 = 0.f;
    if (act) {
        const float* Ab = attn + (size_t)b * PN;
        a0 = Ab[nn0] * 5.0f; a1 = Ab[nn1] * 5.0f;
        a2 = Ab[nn2] * 5.0f; a3 = Ab[nn3] * 5.0f;
    }

    // v = 0.01 * L a
    float v0, v1, v2, v3;
    mv(v0, v1, v2, v3, a0, a1, a2, a3);
    v0 *= 0.01f; v1 *= 0.01f; v2 *= 0.01f; v3 *= 0.01f;

    // v <- (I + R0^(2^stage)) v,  R0 = I - 0.01 L^2
    #pragma unroll
    for (int stage = 0; stage < 4; stage++) {
        float w0 = v0, w1 = v1, w2 = v2, w3 = v3;
        const int k = 1 << stage;
        for (int it = 0; it < k; it++) {
            float t0, t1, t2, t3, s0, s1, s2, s3;
            mv(t0, t1, t2, t3, w0, w1, w2, w3);
            mv(s0, s1, s2, s3, t0, t1, t2, t3);
            w0 -= 0.01f * s0; w1 -= 0.01f * s1;
            w2 -= 0.01f * s2; w3 -= 0.01f * s3;
        }
        v0 += w0; v1 += w1; v2 += w2; v3 += w3;
    }

    if (act) {
        auto shrink = [&](float Fd) {
            return bt * (Fd - tanhf(Fd / (bt + 1e-8f)));
        };
        float f0 = shrink(v0), f1 = shrink(v1), f2 = shrink(v2), f3 = shrink(v3);
        float* Fb = Fmap + (size_t)b * PN;
        float* Gb = Gmap + (size_t)b * PN;
        Fb[nn0] = f0; Fb[nn1] = f1; Fb[nn2] = f2; Fb[nn3] = f3;
        Gb[nn0] = 1.0f + f0; Gb[nn1] = 1.0f + f1;
        Gb[nn2] = 1.0f + f2; Gb[nn3] = 1.0f + f3;
    }
}

// ---------------------------------------------------------------------------
// Kernel 3: S_new = S * G. grid (147, B): each block handles 1024 consecutive
// floats of one batch; G row (196 floats + 3 wrap) staged in LDS.
// ---------------------------------------------------------------------------
__global__ __launch_bounds__(256) void adb_scale(
    const float* __restrict__ S, const float* __restrict__ Gmap,
    float* __restrict__ out)
{
    const int b   = blockIdx.y;
    const int tid = threadIdx.x;

    __shared__ float Gs[PN + 3];
    const float* Gb = Gmap + (size_t)b * PN;
    if (tid < PN / 4) ((float4*)Gs)[tid] = ((const float4*)Gb)[tid];
    if (tid >= 64 && tid < 67) Gs[PN + (tid - 64)] = Gb[tid - 64];  // wrap
    __syncthreads();

    const int off = blockIdx.x * 1024 + tid * 4;   // < 150528
    const int n0  = off % PN;                      // magic-mul, constant PN
    const size_t base = (size_t)b * PC * PN + off;
    float4 sv = *(const float4*)(S + base);
    float4 o;
    o.x = sv.x * Gs[n0];
    o.y = sv.y * Gs[n0 + 1];
    o.z = sv.z * Gs[n0 + 2];
    o.w = sv.w * Gs[n0 + 3];
    *(float4*)(out + base) = o;
}

extern "C" void kernel_launch(void* const* d_in, const int* in_sizes, int n_in,
                              void* d_out, int out_size, void* d_ws, size_t ws_size,
                              hipStream_t stream) {
    const float* S    = (const float*)d_in[0];
    const float* attn = (const float*)d_in[1];
    const float* lmbd = (const float*)d_in[2];
    const float* beta = (const float*)d_in[3];

    const int B = in_sizes[1] / PN;                    // 256

    float* Snew = (float*)d_out;                       // [B,C,14,14]
    float* Fmap = (float*)d_out + (size_t)B * PC * PN; // [B,1,14,14]
    float* ws   = (float*)d_ws;

    const size_t need8 = ((size_t)B * 8 * 3 * PN + (size_t)B * PN) * sizeof(float);
    const size_t need2 = ((size_t)B * 2 * 3 * PN + (size_t)B * PN) * sizeof(float);
    const size_t need1 = ((size_t)B * 1 * 3 * PN + (size_t)B * PN) * sizeof(float);

    if (ws_size >= need8) {
        float* partials = ws;
        float* Gmap = ws + (size_t)B * 8 * 3 * PN;
        adb_reduce<8><<<dim3(8, B), 256, 0, stream>>>(S, partials);
        adb_solve<8><<<B, 64, 0, stream>>>(partials, attn, lmbd, beta, Fmap, Gmap);
        adb_scale<<<dim3((PC * PN) / 1024, B), 256, 0, stream>>>(S, Gmap, Snew);
    } else if (ws_size >= need2) {
        float* partials = ws;
        float* Gmap = ws + (size_t)B * 2 * 3 * PN;
        adb_reduce<2><<<dim3(2, B), 256, 0, stream>>>(S, partials);
        adb_solve<2><<<B, 64, 0, stream>>>(partials, attn, lmbd, beta, Fmap, Gmap);
        adb_scale<<<dim3((PC * PN) / 1024, B), 256, 0, stream>>>(S, Gmap, Snew);
    } else {
        // minimal-scratch fallback
        float* partials = ws;
        float* Gmap = ws + (size_t)B * 1 * 3 * PN;
        (void)need1;
        adb_reduce<1><<<dim3(1, B), 256, 0, stream>>>(S, partials);
        adb_solve<1><<<B, 64, 0, stream>>>(partials, attn, lmbd, beta, Fmap, Gmap);
        adb_scale<<<dim3((PC * PN) / 1024, B), 256, 0, stream>>>(S, Gmap, Snew);
    }
}

// Round 4
// 297.324 us; speedup vs baseline: 1.0500x; 1.0081x over previous
//
#include <hip/hip_runtime.h>
#include <cstdint>

#define PN 196   // 14*14 patches
#define PC 768   // channels
#define KC 16    // channel rows staged per chunk

typedef float f32x4_t __attribute__((ext_vector_type(4)));  // clang vector:
// __builtin_nontemporal_store requires a clang vector type, NOT HIP float4.

// ---------------------------------------------------------------------------
// Kernel 1: partial channel reduction. grid (NCH, B). Each block reduces
// PC/NCH channels of one batch into 3 partial dot-product rows (symmetry:
// acc_l[n] = acc_r[n-1], acc_u[n] = acc_d[n-14], so only s/r/d needed):
//   acc_s[n] = sum_c S[c][n]^2
//   acc_r[n] = sum_c S[c][n]*S[c][n+1]   (consumed only where j<13)
//   acc_d[n] = sum_c S[c][n]*S[c][n+14]  (consumed only where i<13)
// HBM-bound at ~25 us (154 MB read); the LDS stencil hides under the stream.
// Reads S with NORMAL loads on purpose: this read populates L3 so adb_scale's
// re-read of S hits cache.
// ---------------------------------------------------------------------------
template<int NCH>
__global__ __launch_bounds__(256) void adb_reduce(
    const float* __restrict__ S, float* __restrict__ partials)
{
    constexpr int CPB = PC / NCH;
    const int b   = blockIdx.y;
    const int ch  = blockIdx.x;
    const int tid = threadIdx.x;

    __shared__ __align__(16) float rows[KC * PN + 16];

    const float* Sb = S + (size_t)b * PC * PN + (size_t)ch * CPB * PN;

    const bool lane = tid < PN;
    const int n = lane ? tid : 0;

    float acc_s = 0.f, acc_r = 0.f, acc_d = 0.f;

    for (int c0 = 0; c0 < CPB; c0 += KC) {
        __syncthreads();
        const float4* src = (const float4*)(Sb + c0 * PN);
        float4* dst = (float4*)rows;
        #pragma unroll
        for (int k = 0; k < 4; k++) {            // 784 float4s, 256 threads
            int idx = tid + k * 256;
            if (idx < KC * PN / 4) dst[idx] = src[idx];
        }
        __syncthreads();
        if (lane) {
            const float* r0 = rows + n;
            #pragma unroll
            for (int cc = 0; cc < KC; cc++) {
                const float* r = r0 + cc * PN;
                float s = r[0];
                acc_s += s * s;
                acc_r += s * r[1];
                acc_d += s * r[14];
            }
        }
    }

    if (lane) {
        float* P = partials + ((size_t)b * NCH + ch) * 3 * PN;
        P[0 * PN + n] = acc_s;
        P[1 * PN + n] = acc_r;
        P[2 * PN + n] = acc_d;
    }
}

// ---------------------------------------------------------------------------
// Kernel 2: per-batch solve, ONE WAVE per batch, ZERO barriers.
// Lane L (0..48) owns a 2x2 node block at (2*i2, 2*j2); all neighbor exchange
// is 8 __shfl per matvec. Factored Newton-Schulz:
//   X4 = X0 (I+R0)(I+R0^2)(I+R0^4)(I+R0^8),  R0 = I - 0.01 L^2
// ---------------------------------------------------------------------------
template<int NCH>
__global__ __launch_bounds__(64) void adb_solve(
    const float* __restrict__ partials, const float* __restrict__ attn,
    const float* __restrict__ lmbd, const float* __restrict__ beta,
    float* __restrict__ Fmap, float* __restrict__ Gmap)
{
    const int b  = blockIdx.x;
    const int L  = threadIdx.x;           // 0..63, active 0..48
    const int i2 = L / 7, j2 = L % 7;
    const bool act = (L < 49) && (i2 < 7);

    const int n00 = act ? ((2 * i2) * 14 + 2 * j2) : 0;
    const int nn0 = n00, nn1 = n00 + 1, nn2 = n00 + 14, nn3 = n00 + 15;

    // --- gather partial sums for the 4 owned nodes -------------------------
    float as0 = 0.f, as1 = 0.f, as2 = 0.f, as3 = 0.f;
    float ar0 = 0.f, ar1 = 0.f, ar2 = 0.f, ar3 = 0.f;
    float ad0 = 0.f, ad1 = 0.f, ad2 = 0.f, ad3 = 0.f;
    if (act) {
        const float* P = partials + (size_t)b * NCH * 3 * PN;
        #pragma unroll
        for (int ch = 0; ch < NCH; ch++) {
            const float* Pc = P + ch * 3 * PN;
            as0 += Pc[nn0]; as1 += Pc[nn1]; as2 += Pc[nn2]; as3 += Pc[nn3];
            ar0 += Pc[PN + nn0]; ar1 += Pc[PN + nn1];
            ar2 += Pc[PN + nn2]; ar3 += Pc[PN + nn3];
            ad0 += Pc[2 * PN + nn0]; ad1 += Pc[2 * PN + nn1];
            ad2 += Pc[2 * PN + nn2]; ad3 += Pc[2 * PN + nn3];
        }
    }

    const float lm = lmbd[0];
    const float bt = beta[0];

    float rn0 = 1.0f / fmaxf(sqrtf(as0), 1e-12f);
    float rn1 = 1.0f / fmaxf(sqrtf(as1), 1e-12f);
    float rn2 = 1.0f / fmaxf(sqrtf(as2), 1e-12f);
    float rn3 = 1.0f / fmaxf(sqrtf(as3), 1e-12f);

    // clamped shuffle source lanes (clamp => coefficient is 0 on that edge)
    const int sl_l = (j2 > 0) ? L - 1 : L;
    const int sl_r = (j2 < 6) ? L + 1 : L;
    const int sl_u = (i2 > 0) ? L - 7 : L;
    const int sl_d = (i2 < 6) ? L + 7 : L;

    // neighbor norms / sums needed for coefficient construction
    float rnL0 = __shfl(rn1, sl_l, 64);   // left  of n00 = (L-1).n01
    float rnL2 = __shfl(rn3, sl_l, 64);   // left  of n10 = (L-1).n11
    float rnR1 = __shfl(rn0, sl_r, 64);   // right of n01 = (L+1).n00
    float rnR3 = __shfl(rn2, sl_r, 64);   // right of n11 = (L+1).n10
    float rnU0 = __shfl(rn2, sl_u, 64);   // up    of n00 = (L-7).n10
    float rnU1 = __shfl(rn3, sl_u, 64);   // up    of n01 = (L-7).n11
    float rnD2 = __shfl(rn0, sl_d, 64);   // down  of n10 = (L+7).n00
    float rnD3 = __shfl(rn1, sl_d, 64);   // down  of n11 = (L+7).n01
    float srL0 = __shfl(ar1, sl_l, 64);   // srs[il] for n00
    float srL2 = __shfl(ar3, sl_l, 64);   // srs[il] for n10
    float sdU0 = __shfl(ad2, sl_u, 64);   // sds[iu] for n00
    float sdU1 = __shfl(ad3, sl_u, 64);   // sds[iu] for n01

    // per-node edge masks
    const bool hl0 = (j2 > 0), hl2 = (j2 > 0);
    const bool hr1 = (j2 < 6), hr3 = (j2 < 6);
    const bool hu0 = (i2 > 0), hu1 = (i2 > 0);
    const bool hd2 = (i2 < 6), hd3 = (i2 < 6);

    const float deg0 = (hl0 ? 1.f : 0.f) + 1.f + (hu0 ? 1.f : 0.f) + 1.f;
    const float deg1 = 1.f + (hr1 ? 1.f : 0.f) + (hu1 ? 1.f : 0.f) + 1.f;
    const float deg2 = (hl2 ? 1.f : 0.f) + 1.f + 1.f + (hd2 ? 1.f : 0.f);
    const float deg3 = 1.f + (hr3 ? 1.f : 0.f) + 1.f + (hd3 ? 1.f : 0.f);

    auto cdiag = [&](float as, float rn, float deg) {
        float Enn = (as * rn * rn + 1.f) * 0.5f;
        return deg * (lm * Enn - 1.f) + 1e-6f;
    };
    auto coff = [&](float dot, float rna, float rnb) {
        return 1.f - lm * ((dot * rna * rnb + 1.f) * 0.5f);
    };

    const float Lc0 = cdiag(as0, rn0, deg0);
    const float Lc1 = cdiag(as1, rn1, deg1);
    const float Lc2 = cdiag(as2, rn2, deg2);
    const float Lc3 = cdiag(as3, rn3, deg3);

    const float Ll0 = hl0 ? coff(srL0, rn0, rnL0) : 0.f;
    const float Ll1 =       coff(ar0,  rn1, rn0);         // il = n00 (own)
    const float Ll2 = hl2 ? coff(srL2, rn2, rnL2) : 0.f;
    const float Ll3 =       coff(ar2,  rn3, rn2);         // il = n10 (own)

    const float Lr0 =       coff(ar0,  rn0, rn1);         // ir = n01 (own)
    const float Lr1 = hr1 ? coff(ar1,  rn1, rnR1) : 0.f;
    const float Lr2 =       coff(ar2,  rn2, rn3);         // ir = n11 (own)
    const float Lr3 = hr3 ? coff(ar3,  rn3, rnR3) : 0.f;

    const float Lu0 = hu0 ? coff(sdU0, rn0, rnU0) : 0.f;
    const float Lu1 = hu1 ? coff(sdU1, rn1, rnU1) : 0.f;
    const float Lu2 =       coff(ad0,  rn2, rn0);         // iu = n00 (own)
    const float Lu3 =       coff(ad1,  rn3, rn1);         // iu = n01 (own)

    const float Ld0 =       coff(ad0,  rn0, rn2);         // id = n10 (own)
    const float Ld1 =       coff(ad1,  rn1, rn3);         // id = n11 (own)
    const float Ld2 = hd2 ? coff(ad2,  rn2, rnD2) : 0.f;
    const float Ld3 = hd3 ? coff(ad3,  rn3, rnD3) : 0.f;

    // barrier-free stencil matvec: y = L x (4 nodes per lane, 8 shuffles)
    auto mv = [&](float& y0, float& y1, float& y2, float& y3,
                  float x0, float x1, float x2, float x3) {
        float xl0 = __shfl(x1, sl_l, 64);
        float xl2 = __shfl(x3, sl_l, 64);
        float xr1 = __shfl(x0, sl_r, 64);
        float xr3 = __shfl(x2, sl_r, 64);
        float xu0 = __shfl(x2, sl_u, 64);
        float xu1 = __shfl(x3, sl_u, 64);
        float xd2 = __shfl(x0, sl_d, 64);
        float xd3 = __shfl(x1, sl_d, 64);
        y0 = Lc0 * x0 + Ll0 * xl0 + Lr0 * x1  + Lu0 * xu0 + Ld0 * x2;
        y1 = Lc1 * x1 + Ll1 * x0  + Lr1 * xr1 + Lu1 * xu1 + Ld1 * x3;
        y2 = Lc2 * x2 + Ll2 * xl2 + Lr2 * x3  + Lu2 * x0  + Ld2 * xd2;
        y3 = Lc3 * x3 + Ll3 * x2  + Lr3 * xr3 + Lu3 * x1  + Ld3 * xd3;
    };

    // a = attn * 5
    float a0 = 0.f, a1 = 0.f, a2 = 0.f, a3 = 0.f;
    if (act) {
        const float* Ab = attn + (size_t)b * PN;
        a0 = Ab[nn0] * 5.0f; a1 = Ab[nn1] * 5.0f;
        a2 = Ab[nn2] * 5.0f; a3 = Ab[nn3] * 5.0f;
    }

    // v = 0.01 * L a
    float v0, v1, v2, v3;
    mv(v0, v1, v2, v3, a0, a1, a2, a3);
    v0 *= 0.01f; v1 *= 0.01f; v2 *= 0.01f; v3 *= 0.01f;

    // v <- (I + R0^(2^stage)) v,  R0 = I - 0.01 L^2
    #pragma unroll
    for (int stage = 0; stage < 4; stage++) {
        float w0 = v0, w1 = v1, w2 = v2, w3 = v3;
        const int k = 1 << stage;
        for (int it = 0; it < k; it++) {
            float t0, t1, t2, t3, s0, s1, s2, s3;
            mv(t0, t1, t2, t3, w0, w1, w2, w3);
            mv(s0, s1, s2, s3, t0, t1, t2, t3);
            w0 -= 0.01f * s0; w1 -= 0.01f * s1;
            w2 -= 0.01f * s2; w3 -= 0.01f * s3;
        }
        v0 += w0; v1 += w1; v2 += w2; v3 += w3;
    }

    if (act) {
        auto shrink = [&](float Fd) {
            return bt * (Fd - tanhf(Fd / (bt + 1e-8f)));
        };
        float f0 = shrink(v0), f1 = shrink(v1), f2 = shrink(v2), f3 = shrink(v3);
        float* Fb = Fmap + (size_t)b * PN;
        float* Gb = Gmap + (size_t)b * PN;
        Fb[nn0] = f0; Fb[nn1] = f1; Fb[nn2] = f2; Fb[nn3] = f3;
        Gb[nn0] = 1.0f + f0; Gb[nn1] = 1.0f + f1;
        Gb[nn2] = 1.0f + f2; Gb[nn3] = 1.0f + f3;
    }
}

// ---------------------------------------------------------------------------
// Kernel 3: S_new = S * G. grid (49, B): each block handles 3072 consecutive
// floats of one batch (3 float4 per thread, loads hoisted for MLP); G row
// staged in LDS. S is loaded NORMALLY (hits L3, populated by adb_reduce);
// S_new is stored NON-TEMPORALLY so the 154 MB write stream does not
// allocate in L2/L3 and evict the S lines scale still needs (S + out =
// 308 MB > 256 MB L3 would otherwise thrash).
// ---------------------------------------------------------------------------
__global__ __launch_bounds__(256) void adb_scale(
    const float* __restrict__ S, const float* __restrict__ Gmap,
    float* __restrict__ out)
{
    const int b   = blockIdx.y;
    const int tid = threadIdx.x;

    __shared__ float Gs[PN + 3];
    const float* Gb = Gmap + (size_t)b * PN;
    if (tid < PN / 4) ((float4*)Gs)[tid] = ((const float4*)Gb)[tid];
    if (tid >= 64 && tid < 67) Gs[PN + (tid - 64)] = Gb[tid - 64];  // wrap
    __syncthreads();

    const int off0 = blockIdx.x * 3072 + tid * 4;          // 49*3072 = 150528
    const size_t bb = (size_t)b * PC * PN;

    // three independent load chains, hoisted
    f32x4_t sv0 = *(const f32x4_t*)(S + bb + off0);
    f32x4_t sv1 = *(const f32x4_t*)(S + bb + off0 + 1024);
    f32x4_t sv2 = *(const f32x4_t*)(S + bb + off0 + 2048);

    const int n0 = (off0)        % PN;                     // magic-mul
    const int n1 = (off0 + 1024) % PN;
    const int n2 = (off0 + 2048) % PN;

    f32x4_t o0, o1, o2;
    o0.x = sv0.x * Gs[n0];     o0.y = sv0.y * Gs[n0 + 1];
    o0.z = sv0.z * Gs[n0 + 2]; o0.w = sv0.w * Gs[n0 + 3];
    o1.x = sv1.x * Gs[n1];     o1.y = sv1.y * Gs[n1 + 1];
    o1.z = sv1.z * Gs[n1 + 2]; o1.w = sv1.w * Gs[n1 + 3];
    o2.x = sv2.x * Gs[n2];     o2.y = sv2.y * Gs[n2 + 1];
    o2.z = sv2.z * Gs[n2 + 2]; o2.w = sv2.w * Gs[n2 + 3];

    __builtin_nontemporal_store(o0, (f32x4_t*)(out + bb + off0));
    __builtin_nontemporal_store(o1, (f32x4_t*)(out + bb + off0 + 1024));
    __builtin_nontemporal_store(o2, (f32x4_t*)(out + bb + off0 + 2048));
}

extern "C" void kernel_launch(void* const* d_in, const int* in_sizes, int n_in,
                              void* d_out, int out_size, void* d_ws, size_t ws_size,
                              hipStream_t stream) {
    const float* S    = (const float*)d_in[0];
    const float* attn = (const float*)d_in[1];
    const float* lmbd = (const float*)d_in[2];
    const float* beta = (const float*)d_in[3];

    const int B = in_sizes[1] / PN;                    // 256

    float* Snew = (float*)d_out;                       // [B,C,14,14]
    float* Fmap = (float*)d_out + (size_t)B * PC * PN; // [B,1,14,14]
    float* ws   = (float*)d_ws;

    const size_t need8 = ((size_t)B * 8 * 3 * PN + (size_t)B * PN) * sizeof(float);
    const size_t need2 = ((size_t)B * 2 * 3 * PN + (size_t)B * PN) * sizeof(float);
    const size_t need1 = ((size_t)B * 1 * 3 * PN + (size_t)B * PN) * sizeof(float);

    if (ws_size >= need8) {
        float* partials = ws;
        float* Gmap = ws + (size_t)B * 8 * 3 * PN;
        adb_reduce<8><<<dim3(8, B), 256, 0, stream>>>(S, partials);
        adb_solve<8><<<B, 64, 0, stream>>>(partials, attn, lmbd, beta, Fmap, Gmap);
        adb_scale<<<dim3((PC * PN) / 3072, B), 256, 0, stream>>>(S, Gmap, Snew);
    } else if (ws_size >= need2) {
        float* partials = ws;
        float* Gmap = ws + (size_t)B * 2 * 3 * PN;
        adb_reduce<2><<<dim3(2, B), 256, 0, stream>>>(S, partials);
        adb_solve<2><<<B, 64, 0, stream>>>(partials, attn, lmbd, beta, Fmap, Gmap);
        adb_scale<<<dim3((PC * PN) / 3072, B), 256, 0, stream>>>(S, Gmap, Snew);
    } else {
        // minimal-scratch fallback
        float* partials = ws;
        float* Gmap = ws + (size_t)B * 1 * 3 * PN;
        (void)need1;
        adb_reduce<1><<<dim3(1, B), 256, 0, stream>>>(S, partials);
        adb_solve<1><<<B, 64, 0, stream>>>(partials, attn, lmbd, beta, Fmap, Gmap);
        adb_scale<<<dim3((PC * PN) / 3072, B), 256, 0, stream>>>(S, Gmap, Snew);
    }
}

// Round 5
// 292.832 us; speedup vs baseline: 1.0661x; 1.0153x over previous
//
#include <hip/hip_runtime.h>
#include <cstdint>

#define PN 196   // 14*14 patches
#define PC 768   // channels
#define KC 16    // channel rows staged per chunk
#define NG 4     // thread groups of 256 within the 1024-thread block
#define CPG (PC / NG)   // 192 channels per group

typedef float f32x4_t __attribute__((ext_vector_type(4)));  // clang vector:
// __builtin_nontemporal_store requires a clang vector type, NOT HIP float4.

// ---------------------------------------------------------------------------
// Fully fused kernel: one 1024-thread block per batch (grid = B = 256 ->
// exactly 1 block/CU, 16 waves).
//   Phase 1 (reduce): 4 groups x 256 threads; group g streams channels
//     [g*192,(g+1)*192) through its own LDS buffer and accumulates the 3
//     symmetric stencil rows (acc_l[n]=acc_r[n-1], acc_u[n]=acc_d[n-14]):
//       acc_s[n] = sum_c S[c][n]^2
//       acc_r[n] = sum_c S[c][n]*S[c][n+1]   (consumed only where j<13)
//       acc_d[n] = sum_c S[c][n]*S[c][n+14]  (consumed only where i<13)
//     Unconditional padded reads; boundary garbage provably never consumed.
//     4 group partials combined in LDS.
//   Phase 2 (solve): wave 0 only, zero barriers. Lane L (0..48) owns a 2x2
//     node block; neighbor exchange via 8 __shfl per matvec. Factored
//     Newton-Schulz X4 = X0 (I+R0)(I+R0^2)(I+R0^4)(I+R0^8), R0 = I-0.01 L^2.
//     Emits G = 1+Fdiff into LDS (float4-aliasable) and Fmap to global.
//   Phase 3 (scale): all 1024 threads re-read S (L3-hot: this block streamed
//     its 602 KB in phase 1) and nt-store S*G. G lookup is ONE ds_read_b128
//     (Gq[idx%49]) instead of 4 conflicted scalar reads.
// No workspace, no partials round-trip, no inter-kernel gaps.
// LDS: 4*(16*196+16)*4 + 3*4*196*4 + 196*4 ~= 60.6 KB.
// ---------------------------------------------------------------------------
__global__ __launch_bounds__(1024) void adb_fused(
    const float* __restrict__ S, const float* __restrict__ attn,
    const float* __restrict__ lmbd, const float* __restrict__ beta,
    float* __restrict__ out, float* __restrict__ Fmap)
{
    const int b   = blockIdx.x;
    const int tid = threadIdx.x;
    const int g   = tid >> 8;          // group 0..3
    const int t   = tid & 255;         // lane within group

    __shared__ __align__(16) float rows[NG][KC * PN + 16];
    __shared__ float pS[NG][PN];
    __shared__ float pR[NG][PN];
    __shared__ float pD[NG][PN];
    __shared__ __align__(16) float Gs[PN];   // 49 float4s

    const size_t bbase = (size_t)b * PC * PN;

    // ---- solve-wave early state (wave 0): hoist attn/scalar loads so their
    // latency hides under the reduce stream ------------------------------
    const bool sw  = (tid < 64);
    const int  i2  = tid / 7, j2 = tid % 7;       // meaningful for tid<49
    const bool act = sw && (tid < 49);
    const int  n00 = act ? ((2 * i2) * 14 + 2 * j2) : 0;
    float a0 = 0.f, a1 = 0.f, a2 = 0.f, a3 = 0.f, lm = 0.f, bt = 0.f;
    if (sw) {
        lm = lmbd[0];
        bt = beta[0];
        if (act) {
            const float* Ab = attn + (size_t)b * PN;
            a0 = Ab[n00]      * 5.0f;
            a1 = Ab[n00 + 1]  * 5.0f;
            a2 = Ab[n00 + 14] * 5.0f;
            a3 = Ab[n00 + 15] * 5.0f;
        }
    }

    // ======================= Phase 1: reduce ==============================
    const bool lane = t < PN;
    const int  n    = lane ? t : 0;

    const float* Sg = S + bbase + (size_t)g * CPG * PN;

    float acc_s = 0.f, acc_r = 0.f, acc_d = 0.f;

    for (int c0 = 0; c0 < CPG; c0 += KC) {
        __syncthreads();
        const float4* src = (const float4*)(Sg + c0 * PN);
        float4* dst = (float4*)rows[g];
        #pragma unroll
        for (int k = 0; k < 4; k++) {          // 784 float4s, 256 threads
            int idx = t + k * 256;
            if (idx < KC * PN / 4) dst[idx] = src[idx];
        }
        __syncthreads();
        if (lane) {
            const float* r0 = rows[g] + n;
            #pragma unroll
            for (int cc = 0; cc < KC; cc++) {
                const float* r = r0 + cc * PN;
                float s = r[0];
                acc_s += s * s;
                acc_r += s * r[1];
                acc_d += s * r[14];
            }
        }
    }

    if (lane) { pS[g][n] = acc_s; pR[g][n] = acc_r; pD[g][n] = acc_d; }
    __syncthreads();

    // combine 4 group partials into row 0 of each array
    if (tid < 3 * PN) {
        const int axis = tid / PN;             // magic-mul
        const int nn   = tid - axis * PN;
        float* base = (axis == 0) ? &pS[0][0]
                    : (axis == 1) ? &pR[0][0] : &pD[0][0];
        base[nn] = base[nn] + base[PN + nn] + base[2 * PN + nn]
                 + base[3 * PN + nn];
    }
    __syncthreads();

    // ======================= Phase 2: solve (wave 0) ======================
    if (sw) {
        const int L = tid;

        const float as0 = pS[0][n00],      as1 = pS[0][n00 + 1];
        const float as2 = pS[0][n00 + 14], as3 = pS[0][n00 + 15];
        const float ar0 = pR[0][n00],      ar1 = pR[0][n00 + 1];
        const float ar2 = pR[0][n00 + 14], ar3 = pR[0][n00 + 15];
        const float ad0 = pD[0][n00],      ad1 = pD[0][n00 + 1];
        const float ad2 = pD[0][n00 + 14], ad3 = pD[0][n00 + 15];

        float rn0 = 1.0f / fmaxf(sqrtf(as0), 1e-12f);
        float rn1 = 1.0f / fmaxf(sqrtf(as1), 1e-12f);
        float rn2 = 1.0f / fmaxf(sqrtf(as2), 1e-12f);
        float rn3 = 1.0f / fmaxf(sqrtf(as3), 1e-12f);

        // clamped shuffle source lanes (clamp => coefficient is 0 there)
        const int sl_l = (j2 > 0) ? L - 1 : L;
        const int sl_r = (j2 < 6) ? L + 1 : L;
        const int sl_u = (i2 > 0) ? L - 7 : L;
        const int sl_d = (i2 < 6) ? L + 7 : L;

        float rnL0 = __shfl(rn1, sl_l, 64);
        float rnL2 = __shfl(rn3, sl_l, 64);
        float rnR1 = __shfl(rn0, sl_r, 64);
        float rnR3 = __shfl(rn2, sl_r, 64);
        float rnU0 = __shfl(rn2, sl_u, 64);
        float rnU1 = __shfl(rn3, sl_u, 64);
        float rnD2 = __shfl(rn0, sl_d, 64);
        float rnD3 = __shfl(rn1, sl_d, 64);
        float srL0 = __shfl(ar1, sl_l, 64);
        float srL2 = __shfl(ar3, sl_l, 64);
        float sdU0 = __shfl(ad2, sl_u, 64);
        float sdU1 = __shfl(ad3, sl_u, 64);

        const bool hl = (j2 > 0), hr = (j2 < 6), hu = (i2 > 0), hd = (i2 < 6);

        const float deg0 = (hl ? 1.f : 0.f) + 1.f + (hu ? 1.f : 0.f) + 1.f;
        const float deg1 = 1.f + (hr ? 1.f : 0.f) + (hu ? 1.f : 0.f) + 1.f;
        const float deg2 = (hl ? 1.f : 0.f) + 1.f + 1.f + (hd ? 1.f : 0.f);
        const float deg3 = 1.f + (hr ? 1.f : 0.f) + 1.f + (hd ? 1.f : 0.f);

        auto cdiag = [&](float as, float rn, float deg) {
            float Enn = (as * rn * rn + 1.f) * 0.5f;
            return deg * (lm * Enn - 1.f) + 1e-6f;
        };
        auto coff = [&](float dot, float rna, float rnb) {
            return 1.f - lm * ((dot * rna * rnb + 1.f) * 0.5f);
        };

        const float Lc0 = cdiag(as0, rn0, deg0);
        const float Lc1 = cdiag(as1, rn1, deg1);
        const float Lc2 = cdiag(as2, rn2, deg2);
        const float Lc3 = cdiag(as3, rn3, deg3);

        const float Ll0 = hl ? coff(srL0, rn0, rnL0) : 0.f;
        const float Ll1 =      coff(ar0,  rn1, rn0);
        const float Ll2 = hl ? coff(srL2, rn2, rnL2) : 0.f;
        const float Ll3 =      coff(ar2,  rn3, rn2);

        const float Lr0 =      coff(ar0,  rn0, rn1);
        const float Lr1 = hr ? coff(ar1,  rn1, rnR1) : 0.f;
        const float Lr2 =      coff(ar2,  rn2, rn3);
        const float Lr3 = hr ? coff(ar3,  rn3, rnR3) : 0.f;

        const float Lu0 = hu ? coff(sdU0, rn0, rnU0) : 0.f;
        const float Lu1 = hu ? coff(sdU1, rn1, rnU1) : 0.f;
        const float Lu2 =      coff(ad0,  rn2, rn0);
        const float Lu3 =      coff(ad1,  rn3, rn1);

        const float Ld0 =      coff(ad0,  rn0, rn2);
        const float Ld1 =      coff(ad1,  rn1, rn3);
        const float Ld2 = hd ? coff(ad2,  rn2, rnD2) : 0.f;
        const float Ld3 = hd ? coff(ad3,  rn3, rnD3) : 0.f;

        auto mv = [&](float& y0, float& y1, float& y2, float& y3,
                      float x0, float x1, float x2, float x3) {
            float xl0 = __shfl(x1, sl_l, 64);
            float xl2 = __shfl(x3, sl_l, 64);
            float xr1 = __shfl(x0, sl_r, 64);
            float xr3 = __shfl(x2, sl_r, 64);
            float xu0 = __shfl(x2, sl_u, 64);
            float xu1 = __shfl(x3, sl_u, 64);
            float xd2 = __shfl(x0, sl_d, 64);
            float xd3 = __shfl(x1, sl_d, 64);
            y0 = Lc0 * x0 + Ll0 * xl0 + Lr0 * x1  + Lu0 * xu0 + Ld0 * x2;
            y1 = Lc1 * x1 + Ll1 * x0  + Lr1 * xr1 + Lu1 * xu1 + Ld1 * x3;
            y2 = Lc2 * x2 + Ll2 * xl2 + Lr2 * x3  + Lu2 * x0  + Ld2 * xd2;
            y3 = Lc3 * x3 + Ll3 * x2  + Lr3 * xr3 + Lu3 * x1  + Ld3 * xd3;
        };

        float v0, v1, v2, v3;
        mv(v0, v1, v2, v3, a0, a1, a2, a3);
        v0 *= 0.01f; v1 *= 0.01f; v2 *= 0.01f; v3 *= 0.01f;

        #pragma unroll
        for (int stage = 0; stage < 4; stage++) {
            float w0 = v0, w1 = v1, w2 = v2, w3 = v3;
            const int k = 1 << stage;
            for (int it = 0; it < k; it++) {
                float t0, t1, t2, t3, s0, s1, s2, s3;
                mv(t0, t1, t2, t3, w0, w1, w2, w3);
                mv(s0, s1, s2, s3, t0, t1, t2, t3);
                w0 -= 0.01f * s0; w1 -= 0.01f * s1;
                w2 -= 0.01f * s2; w3 -= 0.01f * s3;
            }
            v0 += w0; v1 += w1; v2 += w2; v3 += w3;
        }

        if (act) {
            auto shrink = [&](float Fd) {
                return bt * (Fd - tanhf(Fd / (bt + 1e-8f)));
            };
            float f0 = shrink(v0), f1 = shrink(v1);
            float f2 = shrink(v2), f3 = shrink(v3);
            float* Fb = Fmap + (size_t)b * PN;
            Fb[n00]      = f0; Fb[n00 + 1]  = f1;
            Fb[n00 + 14] = f2; Fb[n00 + 15] = f3;
            Gs[n00]      = 1.0f + f0; Gs[n00 + 1]  = 1.0f + f1;
            Gs[n00 + 14] = 1.0f + f2; Gs[n00 + 15] = 1.0f + f3;
        }
    }
    __syncthreads();

    // ======================= Phase 3: scale ===============================
    // S re-read is L3-hot (this block streamed its own 602 KB in phase 1).
    // One ds_read_b128 per float4 (Gq[idx%49]); nt stores keep S_new out of
    // L2/L3 so other blocks' S stays resident.
    const f32x4_t* __restrict__ Gq = (const f32x4_t*)Gs;
    const float*   __restrict__ Sb = S + bbase;
    float*         __restrict__ Ob = out + bbase;

    #pragma unroll 4
    for (int k = 0; k < 36; k++) {
        const int idx = k * 1024 + tid;        // < 36864
        const int q   = idx % 49;              // magic-mul
        f32x4_t sv = *(const f32x4_t*)(Sb + (size_t)idx * 4);
        f32x4_t o  = sv * Gq[q];
        __builtin_nontemporal_store(o, (f32x4_t*)(Ob + (size_t)idx * 4));
    }
    if (tid < 768) {                           // tail: 37632 - 36864
        const int idx = 36 * 1024 + tid;
        const int q   = idx % 49;
        f32x4_t sv = *(const f32x4_t*)(Sb + (size_t)idx * 4);
        f32x4_t o  = sv * Gq[q];
        __builtin_nontemporal_store(o, (f32x4_t*)(Ob + (size_t)idx * 4));
    }
}

extern "C" void kernel_launch(void* const* d_in, const int* in_sizes, int n_in,
                              void* d_out, int out_size, void* d_ws, size_t ws_size,
                              hipStream_t stream) {
    const float* S    = (const float*)d_in[0];
    const float* attn = (const float*)d_in[1];
    const float* lmbd = (const float*)d_in[2];
    const float* beta = (const float*)d_in[3];

    const int B = in_sizes[1] / PN;                    // 256

    float* Snew = (float*)d_out;                       // [B,C,14,14]
    float* Fmap = (float*)d_out + (size_t)B * PC * PN; // [B,1,14,14]
    (void)d_ws; (void)ws_size;                         // no workspace needed

    adb_fused<<<B, 1024, 0, stream>>>(S, attn, lmbd, beta, Snew, Fmap);
}